// Round 12
// baseline (31.791 us; speedup 1.0000x reference)
//
#include <hip/hip_runtime.h>
#include <hip/hip_bf16.h>

#define MM 4096
#define NN 512
#define RR 32

__device__ __forceinline__ float softplus_f(float x) {
    return x > 20.0f ? x : log1pf(__expf(x));
}

__device__ __forceinline__ int bitrev6(int l) {
    return ((l & 1) << 5) | ((l & 2) << 3) | ((l & 4) << 1) |
           ((l & 8) >> 1) | ((l & 16) >> 3) | ((l & 32) >> 5);
}

// In-register 64-point DIF FFT across the 64 lanes of a wave.
__device__ __forceinline__ void wave_fft64(float& xr, float& xi) {
#pragma unroll
    for (int s = 32; s >= 1; s >>= 1) {
        const float pr = __shfl_xor(xr, s, 64);
        const float pi = __shfl_xor(xi, s, 64);
        const int   lane = threadIdx.x & 63;
        const bool  hi = (lane & s) != 0;
        const float ur = xr + pr, ui = xi + pi;
        const float vr = pr - xr, vi = pi - xi;
        const int   j  = lane & (s - 1);
        const float rev = (float)j * (1.0f / (float)(2 * s));   // [0, 0.5)
        const float ct = __builtin_amdgcn_cosf(rev);
        const float st = __builtin_amdgcn_sinf(rev);
        const float wr = fmaf(vr, ct,   vi * st);   // v * (ct - i st)
        const float wi = fmaf(vi, ct, -(vr * st));
        xr = hi ? wr : ur;
        xi = hi ? wi : ui;
    }
}

// ---------------------------------------------------------------------------
// FFT step 1 (proven): FFT-64 over n2, twiddle, transposed store.
// ---------------------------------------------------------------------------
__global__ __launch_bounds__(256) void fft64_step1(const float* __restrict__ H,
                                                   float2* __restrict__ zbuf) {
    const int wave = (blockIdx.x * 256 + threadIdx.x) >> 6;   // 0..2047
    const int lane = threadIdx.x & 63;                        // n2
    const int d    = wave >> 6;                               // 0..31
    const int n1   = wave & 63;                               // 0..63
    float xr = softplus_f(H[(size_t)d * MM + n1 + 64 * lane]);
    float xi = 0.0f;
    wave_fft64(xr, xi);
    const int k2 = bitrev6(lane);
    const float rev = (float)(n1 * k2) * (1.0f / 4096.0f);    // [0,1)
    const float ct = __builtin_amdgcn_cosf(rev);
    const float st = __builtin_amdgcn_sinf(rev);
    zbuf[(size_t)d * MM + k2 * 64 + n1] =
        make_float2(fmaf(xr, ct, xi * st), fmaf(xi, ct, -(xr * st)));
}

// ---------------------------------------------------------------------------
// FFT step 2 (proven): FFT-64 over n1 (contiguous), scatter.
// ---------------------------------------------------------------------------
__global__ __launch_bounds__(256) void fft64_step2(const float2* __restrict__ zbuf,
                                                   float2* __restrict__ hft) {
    const int wave = (blockIdx.x * 256 + threadIdx.x) >> 6;
    const int lane = threadIdx.x & 63;                        // n1
    const int d    = wave >> 6;
    const int k2   = wave & 63;
    const float2 z = zbuf[(size_t)d * MM + k2 * 64 + lane];
    float xr = z.x, xi = z.y;
    wave_fft64(xr, xi);
    hft[(size_t)d * MM + k2 + 64 * bitrev6(lane)] = make_float2(xr, xi);
}

// ---------------------------------------------------------------------------
// Main kernel — OCCUPANCY-FIRST redesign:
//   * K=2 m-values/thread (+2 Hermitian pairs) -> 524288 threads
//     = 8192 waves = 8 waves/SIMD (4x all previous rounds).
//   * Block 512 thr = 16 rows x 32 lanes; covers 16 n-rows x 64 m-cols.
//     Grid (2048/64, 512/16) = (32, 32) = 1024 blocks = 4 blocks/CU exactly.
//   * Hft tile (32 d x 64 m, 16 KB) staged to LDS once, shared by 16 rows.
//   * k-step rotator (cd,sd) is m-independent -> precomputed per (n,d) in
//     LDS; only 2 trans per (thread,d) in the hot loop.
//   * Rolled d-loop, no register tiles -> low VGPR, high occupancy.
// Math identical to R6/R8-proven Hermitian formulation (absmax 64).
// ---------------------------------------------------------------------------
__global__ __launch_bounds__(512, 4) void shiftnmf_real(const float* __restrict__ W,
                                                        const float* __restrict__ tau,
                                                        const float2* __restrict__ hft,
                                                        float* __restrict__ out) {
    __shared__ float2 htile[RR][64];    // 16 KB: Hft[d][mb..mb+64)
    __shared__ float  spw_s[16][RR];
    __shared__ float  tf_s[16][RR];
    __shared__ float  cu_s[16][RR];
    __shared__ float  su_s[16][RR];
    __shared__ float  cd_s[16][RR];
    __shared__ float  sd_s[16][RR];
    __shared__ float  h2048_s[RR];

    const int tid = threadIdx.x;
    const int mb  = blockIdx.x * 64;       // [0, 2048)
    const int nb  = blockIdx.y * 16;

    {   // per-(row,d) params: 512 threads cover 16 x 32 exactly
        const int nl = tid >> 5;
        const int dd = tid & 31;
        const float w = W[(size_t)(nb + nl) * RR + dd];
        const float t = tau[(size_t)(nb + nl) * RR + dd];
        const float tf = t * (1.0f / (float)MM);
        spw_s[nl][dd] = softplus_f(w);
        tf_s[nl][dd]  = tf;
        const float fr = t - floorf(t);                // frac(tau)
        cu_s[nl][dd] =  __builtin_amdgcn_cosf(fr);     // Re e^{-2pi i tau}
        su_s[nl][dd] = -__builtin_amdgcn_sinf(fr);     // Im e^{-2pi i tau}
        float dl = tf * 32.0f; dl -= floorf(dl);       // k-step rotator
        cd_s[nl][dd] = __builtin_amdgcn_cosf(dl);
        sd_s[nl][dd] = __builtin_amdgcn_sinf(dl);
    }
    // stage Hft tile: 2048 float2, 4 per thread, coalesced rows
#pragma unroll
    for (int j = 0; j < 4; ++j) {
        const int idx = tid + 512 * j;     // [0, 2048)
        const int r   = idx >> 6;          // d row 0..31
        const int cc  = idx & 63;
        htile[r][cc] = hft[(size_t)r * MM + mb + cc];
    }
    if (tid < RR) h2048_s[tid] = hft[(size_t)tid * MM + 2048].x;
    __syncthreads();

    const int g  = tid >> 5;               // row 0..15
    const int ml = tid & 31;
    const int n  = nb + g;
    const float m0f = (float)(mb + ml);

    float accm0 = 0.0f, accm1 = 0.0f, accp0 = 0.0f, accp1 = 0.0f;

    for (int d = 0; d < RR; ++d) {
        const float A  = spw_s[g][d];
        const float tf = tf_s[g][d];
        const float ru = cu_s[g][d];
        const float iu = su_s[g][d];
        const float cd = cd_s[g][d];
        const float sd = sd_s[g][d];

        float r0 = tf * m0f;  r0 -= floorf(r0);        // [0,1)
        const float c0 = __builtin_amdgcn_cosf(r0);
        const float s0 = __builtin_amdgcn_sinf(r0);
        const float ca = A * c0, sa = A * s0;          // phasor, m = mb+ml
        const float cb = ca * cd - sa * sd;            // phasor, m+32
        const float sb = sa * cd + ca * sd;

        const float2 h0 = htile[d][ml];
        const float2 h1 = htile[d][ml + 32];

        // z = A e^{-i phi} h: Re z = c*hx + s*hy ; Im z = c*hy - s*hx
        const float rz0 = fmaf(ca, h0.x,   sa * h0.y);
        const float iz0 = fmaf(ca, h0.y, -(sa * h0.x));
        accm0 += rz0;
        accp0  = fmaf(ru, rz0, fmaf(iu, iz0, accp0));

        const float rz1 = fmaf(cb, h1.x,   sb * h1.y);
        const float iz1 = fmaf(cb, h1.y, -(sb * h1.x));
        accm1 += rz1;
        accp1  = fmaf(ru, rz1, fmaf(iu, iz1, accp1));
    }

    float* orow = out + (size_t)n * MM;
    const int m0 = mb + ml;                 // [0, 2047]
    const int m1 = m0 + 32;
    orow[m0] = accm0;
    orow[m1] = accm1;
    if (m0 != 0) orow[MM - m0] = accp0;     // [2049, 4095]
    orow[MM - m1] = accp1;                  // m1 >= 32, always valid

    // Nyquist column m = 2048 (real bin): one lane per row, bx==0 blocks.
    if (blockIdx.x == 0 && ml == 0) {
        float acc = 0.0f;
        for (int d = 0; d < RR; ++d) {
            float r = tf_s[g][d] * 2048.0f;
            r -= floorf(r);
            acc = fmaf(spw_s[g][d] * h2048_s[d], __builtin_amdgcn_cosf(r), acc);
        }
        orow[2048] = acc;
    }
}

// ---------------------------------------------------------------------------
// Complex-output hedge path (never taken in practice): R5-proven kernel.
// ---------------------------------------------------------------------------
__global__ __launch_bounds__(256) void shiftnmf_cplx(const float* __restrict__ W,
                                                     const float* __restrict__ tau,
                                                     const float2* __restrict__ hft,
                                                     float* __restrict__ out) {
    __shared__ float spw_s[16][RR];
    __shared__ float tau_s[16][RR];
    const int tid = threadIdx.x;
    const int mb  = blockIdx.x * 256;
    const int nb  = blockIdx.y * 16;
    for (int idx = tid; idx < 16 * RR; idx += 256) {
        const int nl = idx >> 5;
        const int dd = idx & 31;
        spw_s[nl][dd] = softplus_f(W[(size_t)(nb + nl) * RR + dd]);
        tau_s[nl][dd] = tau[(size_t)(nb + nl) * RR + dd] * (1.0f / (float)MM);
    }
    __syncthreads();
    const int g  = tid >> 5;
    const int ml = tid & 31;
    const int n0 = g * 2;
    const float m0f = (float)(mb + ml);
    const float2* hcol = hft + mb + ml;
    float accR[2][8], accI[2][8];
#pragma unroll
    for (int j = 0; j < 2; ++j)
#pragma unroll
        for (int k = 0; k < 8; ++k) { accR[j][k] = 0.0f; accI[j][k] = 0.0f; }
    float2 hc[8], hn[8];
#pragma unroll
    for (int k = 0; k < 8; ++k) hc[k] = hcol[32 * k];
    for (int d = 0; d < RR; ++d) {
        const float2* hnp = hcol + (size_t)((d + 1 < RR) ? d + 1 : d) * MM;
#pragma unroll
        for (int k = 0; k < 8; ++k) hn[k] = hnp[32 * k];
#pragma unroll
        for (int j = 0; j < 2; ++j) {
            const float A  = spw_s[n0 + j][d];
            const float tf = tau_s[n0 + j][d];
            float r0 = tf * m0f;  r0 -= floorf(r0);
            float dl = tf * 32.0f; dl -= floorf(dl);
            const float c0 = __builtin_amdgcn_cosf(r0);
            const float s0 = __builtin_amdgcn_sinf(r0);
            const float cd = __builtin_amdgcn_cosf(dl);
            const float sd = __builtin_amdgcn_sinf(dl);
            float ca = A * c0, sa = A * s0;
            float cb = ca * cd - sa * sd;
            float sb = sa * cd + ca * sd;
            const float c2 = fmaf(-2.0f * sd, sd, 1.0f);
            const float s2 = 2.0f * sd * cd;
#pragma unroll
            for (int t4 = 0; t4 < 4; ++t4) {
                const float2 h0 = hc[2 * t4];
                const float2 h1 = hc[2 * t4 + 1];
                accR[j][2*t4]   = fmaf(ca, h0.x, fmaf(sa, h0.y, accR[j][2*t4]));
                accR[j][2*t4+1] = fmaf(cb, h1.x, fmaf(sb, h1.y, accR[j][2*t4+1]));
                accI[j][2*t4]   = fmaf(ca, h0.y, fmaf(-sa, h0.x, accI[j][2*t4]));
                accI[j][2*t4+1] = fmaf(cb, h1.y, fmaf(-sb, h1.x, accI[j][2*t4+1]));
                if (t4 < 3) {
                    const float can = fmaf(ca, c2, -(sa * s2));
                    const float san = fmaf(sa, c2,  (ca * s2));
                    const float cbn = fmaf(cb, c2, -(sb * s2));
                    const float sbn = fmaf(sb, c2,  (cb * s2));
                    ca = can; sa = san; cb = cbn; sb = sbn;
                }
            }
        }
#pragma unroll
        for (int k = 0; k < 8; ++k) hc[k] = hn[k];
    }
#pragma unroll
    for (int j = 0; j < 2; ++j) {
        float2* orow = (float2*)out + (size_t)(nb + n0 + j) * MM + mb + ml;
#pragma unroll
        for (int k = 0; k < 8; ++k)
            orow[32 * k] = make_float2(accR[j][k], accI[j][k]);
    }
}

extern "C" void kernel_launch(void* const* d_in, const int* in_sizes, int n_in,
                              void* d_out, int out_size, void* d_ws, size_t ws_size,
                              hipStream_t stream) {
    const float* W   = (const float*)d_in[0];   // (512, 32)
    const float* H   = (const float*)d_in[1];   // (32, 4096)
    const float* tau = (const float*)d_in[2];   // (512, 32)

    const size_t hft_bytes = (size_t)RR * MM * sizeof(float2);  // 1 MB
    if (ws_size < 2 * hft_bytes) return;        // safe bail (no crash)
    float2* zbuf = (float2*)d_ws;               // step-1 intermediate (1 MB)
    float2* hft  = zbuf + (size_t)RR * MM;      // spectrum (1 MB)

    fft64_step1<<<512, 256, 0, stream>>>(H, zbuf);
    fft64_step2<<<512, 256, 0, stream>>>(zbuf, hft);

    if (out_size >= 2 * NN * MM) {
        dim3 grid(MM / 256, NN / 16);
        shiftnmf_cplx<<<grid, 256, 0, stream>>>(W, tau, hft, (float*)d_out);
    } else {
        dim3 grid(2048 / 64, NN / 16);
        shiftnmf_real<<<grid, 512, 0, stream>>>(W, tau, hft, (float*)d_out);
    }
}

// Round 14
// 28.997 us; speedup vs baseline: 1.0964x; 1.0964x over previous
//
#include <hip/hip_runtime.h>
#include <hip/hip_bf16.h>

#define MM 4096
#define NN 512
#define RR 32

__device__ __forceinline__ float softplus_f(float x) {
    return x > 20.0f ? x : log1pf(__expf(x));
}

__device__ __forceinline__ int bitrev6(int l) {
    return ((l & 1) << 5) | ((l & 2) << 3) | ((l & 4) << 1) |
           ((l & 8) >> 1) | ((l & 16) >> 3) | ((l & 32) >> 5);
}

// In-register 64-point DIF FFT across the 64 lanes of a wave.
__device__ __forceinline__ void wave_fft64(float& xr, float& xi) {
#pragma unroll
    for (int s = 32; s >= 1; s >>= 1) {
        const float pr = __shfl_xor(xr, s, 64);
        const float pi = __shfl_xor(xi, s, 64);
        const int   lane = threadIdx.x & 63;
        const bool  hi = (lane & s) != 0;
        const float ur = xr + pr, ui = xi + pi;
        const float vr = pr - xr, vi = pi - xi;
        const int   j  = lane & (s - 1);
        const float rev = (float)j * (1.0f / (float)(2 * s));   // [0, 0.5)
        const float ct = __builtin_amdgcn_cosf(rev);
        const float st = __builtin_amdgcn_sinf(rev);
        const float wr = fmaf(vr, ct,   vi * st);   // v * (ct - i st)
        const float wi = fmaf(vi, ct, -(vr * st));
        xr = hi ? wr : ur;
        xi = hi ? wi : ui;
    }
}

// ---------------------------------------------------------------------------
// FFT step 1 (proven): FFT-64 over n2, twiddle, transposed store.
// ---------------------------------------------------------------------------
__global__ __launch_bounds__(256) void fft64_step1(const float* __restrict__ H,
                                                   float2* __restrict__ zbuf) {
    const int wave = (blockIdx.x * 256 + threadIdx.x) >> 6;   // 0..2047
    const int lane = threadIdx.x & 63;                        // n2
    const int d    = wave >> 6;                               // 0..31
    const int n1   = wave & 63;                               // 0..63
    float xr = softplus_f(H[(size_t)d * MM + n1 + 64 * lane]);
    float xi = 0.0f;
    wave_fft64(xr, xi);
    const int k2 = bitrev6(lane);
    const float rev = (float)(n1 * k2) * (1.0f / 4096.0f);    // [0,1)
    const float ct = __builtin_amdgcn_cosf(rev);
    const float st = __builtin_amdgcn_sinf(rev);
    zbuf[(size_t)d * MM + k2 * 64 + n1] =
        make_float2(fmaf(xr, ct, xi * st), fmaf(xi, ct, -(xr * st)));
}

// ---------------------------------------------------------------------------
// FFT step 2 (proven): FFT-64 over n1 (contiguous), scatter.
// ---------------------------------------------------------------------------
__global__ __launch_bounds__(256) void fft64_step2(const float2* __restrict__ zbuf,
                                                   float2* __restrict__ hft) {
    const int wave = (blockIdx.x * 256 + threadIdx.x) >> 6;
    const int lane = threadIdx.x & 63;                        // n1
    const int d    = wave >> 6;
    const int k2   = wave & 63;
    const float2 z = zbuf[(size_t)d * MM + k2 * 64 + lane];
    float xr = z.x, xi = z.y;
    wave_fft64(xr, xi);
    hft[(size_t)d * MM + k2 + 64 * bitrev6(lane)] = make_float2(xr, xi);
}

// ---------------------------------------------------------------------------
// Main kernel — LDS-ISSUE-MINIMIZED, tile-size FIXED from R13:
//   htile is [RR][64] float4 (32 KB): 128 float2 per d-row = 64 float4.
//   (R13 declared [RR][32] -> staging overflowed into pw_s and compute read
//    OOB; this was the absmax 1.18e6.)
//  * params packed as ONE float4 (A, tf, ru, iu) -> 1 ds_read_b128 per (t,d)
//  * K=4 CONSECUTIVE m per thread -> 2 ds_read_b128, contiguous 16B/lane
//  * 3 LDS insts / 8 outputs (R12: 8 per 4) — tests the LDS-issue theory
//  * block 512 thr = 16 rows x 32 lanes; tile 16 n x 128 m(half);
//    grid (16, 32) = 512 blocks; LDS 40.1KB -> 2 blocks/CU = 16 waves/CU.
// Math identical to R6/R8/R12-proven Hermitian formulation.
// ---------------------------------------------------------------------------
__global__ __launch_bounds__(512, 2) void shiftnmf_real(const float* __restrict__ W,
                                                        const float* __restrict__ tau,
                                                        const float2* __restrict__ hft,
                                                        float* __restrict__ out) {
    __shared__ float4 htile[RR][64];    // 32 KB: Hft[d][mb..mb+128) as float4
    __shared__ float4 pw_s[16][RR];     // 8 KB: (A, tf, ru, iu) per (row, d)
    __shared__ float  h2048_s[RR];

    const int tid = threadIdx.x;
    const int mb  = blockIdx.x * 128;      // [0, 2048)
    const int nb  = blockIdx.y * 16;

    {   // per-(row,d) params: 512 threads cover 16 x 32 exactly
        const int nl = tid >> 5;
        const int dd = tid & 31;
        const float w = W[(size_t)(nb + nl) * RR + dd];
        const float t = tau[(size_t)(nb + nl) * RR + dd];
        const float tf = t * (1.0f / (float)MM);
        const float fr = t - floorf(t);                        // frac(tau)
        pw_s[nl][dd] = make_float4(softplus_f(w), tf,
                                   __builtin_amdgcn_cosf(fr),   // ru
                                   -__builtin_amdgcn_sinf(fr)); // iu
    }
    {   // stage Hft tile: 32 rows x 64 float4 = 2048 float4, 4 per thread
        float4* hf4 = &htile[0][0];
#pragma unroll
        for (int j = 0; j < 4; ++j) {
            const int idx = tid + 512 * j;          // [0, 2048)
            const int r   = idx >> 6;               // d row 0..31
            const int c   = idx & 63;               // float4 col 0..63
            hf4[idx] = ((const float4*)(hft + (size_t)r * MM + mb))[c];
        }
    }
    if (tid < RR) h2048_s[tid] = hft[(size_t)tid * MM + 2048].x;
    __syncthreads();

    const int g  = tid >> 5;                // row 0..15
    const int ml = tid & 31;
    const int n  = nb + g;
    const int m0 = mb + 4 * ml;             // [0, 2044], multiple of 4
    const float m0f = (float)m0;

    float accm[4] = {0.f, 0.f, 0.f, 0.f};
    float accp[4] = {0.f, 0.f, 0.f, 0.f};

#pragma unroll 2
    for (int d = 0; d < RR; ++d) {
        const float4 P = pw_s[g][d];        // 1 x ds_read_b128
        const float A  = P.x;
        const float tf = P.y;
        const float ru = P.z;
        const float iu = P.w;

        float r0 = tf * m0f;  r0 -= floorf(r0);        // [0,1)
        const float c0 = __builtin_amdgcn_cosf(r0);
        const float s0 = __builtin_amdgcn_sinf(r0);
        float dl = tf - floorf(tf);                    // per-1-m rotator
        const float cd = __builtin_amdgcn_cosf(dl);
        const float sd = __builtin_amdgcn_sinf(dl);
        float ca = A * c0, sa = A * s0;                // phasor at m0

        const float4 q0 = htile[d][2 * ml];            // h[m0], h[m0+1]
        const float4 q1 = htile[d][2 * ml + 1];        // h[m0+2], h[m0+3]

#define PAIR(K, HX, HY)                                                     \
        {                                                                   \
            const float rz = fmaf(ca, HX,   sa * HY);                       \
            const float iz = fmaf(ca, HY, -(sa * HX));                      \
            accm[K] += rz;                                                  \
            accp[K]  = fmaf(ru, rz, fmaf(iu, iz, accp[K]));                 \
        }
#define ROT()                                                               \
        {                                                                   \
            const float can = fmaf(ca, cd, -(sa * sd));                     \
            const float san = fmaf(sa, cd,  (ca * sd));                     \
            ca = can; sa = san;                                             \
        }
        PAIR(0, q0.x, q0.y) ROT()
        PAIR(1, q0.z, q0.w) ROT()
        PAIR(2, q1.x, q1.y) ROT()
        PAIR(3, q1.z, q1.w)
#undef PAIR
#undef ROT
    }

    float* orow = out + (size_t)n * MM;
    // m-side: aligned float4 store
    *(float4*)(orow + m0) = make_float4(accm[0], accm[1], accm[2], accm[3]);
    // Hermitian side: scalar stores (reversed, contiguous across lanes)
    if (m0 != 0) {
#pragma unroll
        for (int k = 0; k < 4; ++k) orow[MM - (m0 + k)] = accp[k];
    } else {
#pragma unroll
        for (int k = 1; k < 4; ++k) orow[MM - k] = accp[k];   // skip m=0 pair
    }

    // Nyquist column m = 2048 (real bin): one lane per row, bx==0 blocks.
    if (blockIdx.x == 0 && ml == 0) {
        float acc = 0.0f;
        for (int d = 0; d < RR; ++d) {
            const float4 P = pw_s[g][d];
            float r = P.y * 2048.0f;
            r -= floorf(r);
            acc = fmaf(P.x * h2048_s[d], __builtin_amdgcn_cosf(r), acc);
        }
        orow[2048] = acc;
    }
}

// ---------------------------------------------------------------------------
// Complex-output hedge path (never taken in practice): R5-proven kernel.
// ---------------------------------------------------------------------------
__global__ __launch_bounds__(256) void shiftnmf_cplx(const float* __restrict__ W,
                                                     const float* __restrict__ tau,
                                                     const float2* __restrict__ hft,
                                                     float* __restrict__ out) {
    __shared__ float spw_s[16][RR];
    __shared__ float tau_s[16][RR];
    const int tid = threadIdx.x;
    const int mb  = blockIdx.x * 256;
    const int nb  = blockIdx.y * 16;
    for (int idx = tid; idx < 16 * RR; idx += 256) {
        const int nl = idx >> 5;
        const int dd = idx & 31;
        spw_s[nl][dd] = softplus_f(W[(size_t)(nb + nl) * RR + dd]);
        tau_s[nl][dd] = tau[(size_t)(nb + nl) * RR + dd] * (1.0f / (float)MM);
    }
    __syncthreads();
    const int g  = tid >> 5;
    const int ml = tid & 31;
    const int n0 = g * 2;
    const float m0f = (float)(mb + ml);
    const float2* hcol = hft + mb + ml;
    float accR[2][8], accI[2][8];
#pragma unroll
    for (int j = 0; j < 2; ++j)
#pragma unroll
        for (int k = 0; k < 8; ++k) { accR[j][k] = 0.0f; accI[j][k] = 0.0f; }
    float2 hc[8], hn[8];
#pragma unroll
    for (int k = 0; k < 8; ++k) hc[k] = hcol[32 * k];
    for (int d = 0; d < RR; ++d) {
        const float2* hnp = hcol + (size_t)((d + 1 < RR) ? d + 1 : d) * MM;
#pragma unroll
        for (int k = 0; k < 8; ++k) hn[k] = hnp[32 * k];
#pragma unroll
        for (int j = 0; j < 2; ++j) {
            const float A  = spw_s[n0 + j][d];
            const float tf = tau_s[n0 + j][d];
            float r0 = tf * m0f;  r0 -= floorf(r0);
            float dl = tf * 32.0f; dl -= floorf(dl);
            const float c0 = __builtin_amdgcn_cosf(r0);
            const float s0 = __builtin_amdgcn_sinf(r0);
            const float cd = __builtin_amdgcn_cosf(dl);
            const float sd = __builtin_amdgcn_sinf(dl);
            float ca = A * c0, sa = A * s0;
            float cb = ca * cd - sa * sd;
            float sb = sa * cd + ca * sd;
            const float c2 = fmaf(-2.0f * sd, sd, 1.0f);
            const float s2 = 2.0f * sd * cd;
#pragma unroll
            for (int t4 = 0; t4 < 4; ++t4) {
                const float2 h0 = hc[2 * t4];
                const float2 h1 = hc[2 * t4 + 1];
                accR[j][2*t4]   = fmaf(ca, h0.x, fmaf(sa, h0.y, accR[j][2*t4]));
                accR[j][2*t4+1] = fmaf(cb, h1.x, fmaf(sb, h1.y, accR[j][2*t4+1]));
                accI[j][2*t4]   = fmaf(ca, h0.y, fmaf(-sa, h0.x, accI[j][2*t4]));
                accI[j][2*t4+1] = fmaf(cb, h1.y, fmaf(-sb, h1.x, accI[j][2*t4+1]));
                if (t4 < 3) {
                    const float can = fmaf(ca, c2, -(sa * s2));
                    const float san = fmaf(sa, c2,  (ca * s2));
                    const float cbn = fmaf(cb, c2, -(sb * s2));
                    const float sbn = fmaf(sb, c2,  (cb * s2));
                    ca = can; sa = san; cb = cbn; sb = sbn;
                }
            }
        }
#pragma unroll
        for (int k = 0; k < 8; ++k) hc[k] = hn[k];
    }
#pragma unroll
    for (int j = 0; j < 2; ++j) {
        float2* orow = (float2*)out + (size_t)(nb + n0 + j) * MM + mb + ml;
#pragma unroll
        for (int k = 0; k < 8; ++k)
            orow[32 * k] = make_float2(accR[j][k], accI[j][k]);
    }
}

extern "C" void kernel_launch(void* const* d_in, const int* in_sizes, int n_in,
                              void* d_out, int out_size, void* d_ws, size_t ws_size,
                              hipStream_t stream) {
    const float* W   = (const float*)d_in[0];   // (512, 32)
    const float* H   = (const float*)d_in[1];   // (32, 4096)
    const float* tau = (const float*)d_in[2];   // (512, 32)

    const size_t hft_bytes = (size_t)RR * MM * sizeof(float2);  // 1 MB
    if (ws_size < 2 * hft_bytes) return;        // safe bail (no crash)
    float2* zbuf = (float2*)d_ws;               // step-1 intermediate (1 MB)
    float2* hft  = zbuf + (size_t)RR * MM;      // spectrum (1 MB)

    fft64_step1<<<512, 256, 0, stream>>>(H, zbuf);
    fft64_step2<<<512, 256, 0, stream>>>(zbuf, hft);

    if (out_size >= 2 * NN * MM) {
        dim3 grid(MM / 256, NN / 16);
        shiftnmf_cplx<<<grid, 256, 0, stream>>>(W, tau, hft, (float*)d_out);
    } else {
        dim3 grid(2048 / 128, NN / 16);
        shiftnmf_real<<<grid, 512, 0, stream>>>(W, tau, hft, (float*)d_out);
    }
}